// Round 2
// baseline (347.516 us; speedup 1.0000x reference)
//
#include <hip/hip_runtime.h>
#include <cstddef>
#include <cstdint>

typedef unsigned short u16;
typedef __attribute__((ext_vector_type(8))) unsigned short ushort8;
typedef __attribute__((ext_vector_type(8))) short bf16x8;   // 8 bf16 bit-patterns (4 VGPRs)
typedef __attribute__((ext_vector_type(4))) float f32x4;

#define DEV __device__ __forceinline__

DEV u16 f2bf(float f){
  uint32_t u = __builtin_bit_cast(uint32_t, f);
  u += 0x7FFFu + ((u >> 16) & 1u);          // RNE
  return (u16)(u >> 16);
}
DEV float silu_f(float x){ return x / (1.f + __expf(-x)); }

// ---------------- transpose fp32 [R][C] -> bf16 [C][R] ----------------
__global__ __launch_bounds__(256) void transpose_bf16_k(const float* __restrict__ in,
                                                        u16* __restrict__ out, int R, int C){
  __shared__ u16 tile[32][33];
  int c0 = blockIdx.x * 32, r0 = blockIdx.y * 32;
  int tx = threadIdx.x, ty = threadIdx.y;     // block (32,8)
  #pragma unroll
  for (int k = 0; k < 4; ++k){
    int r = r0 + ty + k*8, c = c0 + tx;
    float v = (c < C) ? in[(size_t)r * C + c] : 0.f;
    tile[ty + k*8][tx] = f2bf(v);
  }
  __syncthreads();
  #pragma unroll
  for (int k = 0; k < 4; ++k){
    int oc = c0 + ty + k*8, orr = r0 + tx;
    if (oc < C) out[(size_t)oc * R + orr] = tile[tx][ty + k*8];
  }
}

// ---------------- generic bf16-MFMA GEMM with register-prefetch pipeline ------
// C[M,N] = A_fp32[M,K] @ B, B pre-transposed bf16 [N][K] (ldb=K).
// A converted fp32->bf16 while committing regs->LDS.
// MODE: 0 = atomicAdd into out0 (256-wide; split-K via blockIdx.z)
//       1 = +bias, ReLU, LayerNorm(256) -> out0 fp32
//       2 = split store: cols<512 -> out0, else -> out1 (both 512-wide)
//       3 = store cols<48 -> out0 (48-wide)
template<int MODE, int TM, int NT>
__global__ __launch_bounds__(256) void gemm_k(const float* __restrict__ A, int lda,
    const u16* __restrict__ Bt, int ldb, int kchunk,
    float* __restrict__ out0, float* __restrict__ out1,
    const float* __restrict__ bias, const float* __restrict__ lng, const float* __restrict__ lnb)
{
  constexpr int WN = NT / 4, MI = TM / 16, NI = WN / 16;
  extern __shared__ char smem[];
  u16* As = (u16*)smem;                 // TM x 40 (pad 40: 80B rows, 16B-aligned)
  u16* Bs = As + TM * 40;               // NT x 40
  const int tid = threadIdx.x, wave = tid >> 6, lane = tid & 63;
  const int lq = lane >> 4, lr = lane & 15;
  const int m0 = blockIdx.x * TM, n0g = blockIdx.y * NT;
  const int k0base = blockIdx.z * kchunk;

  f32x4 acc[MI][NI];
  #pragma unroll
  for (int i = 0; i < MI; ++i)
    #pragma unroll
    for (int j = 0; j < NI; ++j) acc[i][j] = f32x4{0.f, 0.f, 0.f, 0.f};

  // prefetch thread assignments: A = 8 fp32/thread, B = 1 row (32 bf16)/thread
  const int arow = tid >> 2, ako = (tid & 3) * 8;
  const bool aact = (tid < TM * 4);
  const bool bact = (tid < NT);
  const float* aptr = A + (size_t)(m0 + arow) * lda + k0base + ako;
  const u16*   bptr = Bt + (size_t)(n0g + tid) * ldb + k0base;

  f32x4 fa0{}, fa1{};
  ushort8 bv0{}, bv1{}, bv2{}, bv3{};
  if (aact){ fa0 = *(const f32x4*)aptr; fa1 = *(const f32x4*)(aptr + 4); }
  if (bact){
    const ushort8* bp = (const ushort8*)bptr;
    bv0 = bp[0]; bv1 = bp[1]; bv2 = bp[2]; bv3 = bp[3];
  }

  for (int kk = 0; kk < kchunk; kk += 32){
    // commit prefetched regs to LDS
    if (aact){
      ushort8 o;
      #pragma unroll
      for (int j = 0; j < 4; ++j) o[j] = f2bf(fa0[j]);
      #pragma unroll
      for (int j = 0; j < 4; ++j) o[4 + j] = f2bf(fa1[j]);
      *(ushort8*)(As + arow * 40 + ako) = o;
    }
    if (bact){
      ushort8* dst = (ushort8*)(Bs + tid * 40);
      dst[0] = bv0; dst[1] = bv1; dst[2] = bv2; dst[3] = bv3;
    }
    __syncthreads();
    // issue next tile's global loads; latency overlaps ds_read + MFMA below
    if (kk + 32 < kchunk){
      aptr += 32; bptr += 32;
      if (aact){ fa0 = *(const f32x4*)aptr; fa1 = *(const f32x4*)(aptr + 4); }
      if (bact){
        const ushort8* bp = (const ushort8*)bptr;
        bv0 = bp[0]; bv1 = bp[1]; bv2 = bp[2]; bv3 = bp[3];
      }
    }
    bf16x8 af[MI], bfr[NI];
    #pragma unroll
    for (int mi = 0; mi < MI; ++mi)
      af[mi] = *(const bf16x8*)(As + (mi * 16 + lr) * 40 + lq * 8);
    #pragma unroll
    for (int ni = 0; ni < NI; ++ni)
      bfr[ni] = *(const bf16x8*)(Bs + (wave * WN + ni * 16 + lr) * 40 + lq * 8);
    #pragma unroll
    for (int mi = 0; mi < MI; ++mi)
      #pragma unroll
      for (int ni = 0; ni < NI; ++ni)
        acc[mi][ni] = __builtin_amdgcn_mfma_f32_16x16x32_bf16(af[mi], bfr[ni], acc[mi][ni], 0, 0, 0);
    __syncthreads();
  }

  if constexpr (MODE == 1){
    float* Hs  = (float*)(smem + TM * 80 + NT * 80);   // TM x 257 (pad kills bank conflicts)
    float* mus = Hs + TM * 257;
    float* rss = mus + TM;
    #pragma unroll
    for (int mi = 0; mi < MI; ++mi)
      #pragma unroll
      for (int ni = 0; ni < NI; ++ni)
        #pragma unroll
        for (int r = 0; r < 4; ++r){
          int row_l = mi*16 + lq*4 + r;
          int col_l = wave*WN + ni*16 + lr;
          Hs[row_l*257 + col_l] = fmaxf(acc[mi][ni][r] + bias[col_l], 0.f);
        }
    __syncthreads();
    // per-wave row stats: wave w handles rows w, w+4, ... ; shuffle-reduce 64 lanes
    for (int r = wave; r < TM; r += 4){
      float s = 0.f, s2 = 0.f;
      #pragma unroll
      for (int j = 0; j < 4; ++j){
        float v = Hs[r*257 + lane + j*64];
        s += v; s2 += v*v;
      }
      #pragma unroll
      for (int d = 32; d; d >>= 1){
        s  += __shfl_down(s, d);
        s2 += __shfl_down(s2, d);
      }
      if (lane == 0){
        float mu  = s * (1.f/256.f);
        float var = s2 * (1.f/256.f) - mu*mu;
        mus[r] = mu; rss[r] = rsqrtf(var + 1e-5f);
      }
    }
    __syncthreads();
    for (int idx = tid; idx < TM*256; idx += 256){
      int r = idx >> 8, c = idx & 255;
      float v = (Hs[r*257 + c] - mus[r]) * rss[r] * lng[c] + lnb[c];
      out0[(size_t)(m0 + r) * 256 + c] = v;
    }
  } else {
    #pragma unroll
    for (int mi = 0; mi < MI; ++mi)
      #pragma unroll
      for (int ni = 0; ni < NI; ++ni)
        #pragma unroll
        for (int r = 0; r < 4; ++r){
          float v = acc[mi][ni][r];
          int row  = m0 + mi*16 + lq*4 + r;
          int gcol = n0g + wave*WN + ni*16 + lr;
          if constexpr (MODE == 0){
            atomicAdd(out0 + (size_t)row * 256 + gcol, v);
          } else if constexpr (MODE == 2){
            if (gcol < 512) out0[(size_t)row * 512 + gcol] = v;
            else            out1[(size_t)row * 512 + gcol - 512] = v;
          } else {
            if (gcol < 48)  out0[(size_t)row * 48 + gcol] = v;
          }
        }
  }
}

// ---------------- depthwise causal conv (k=4) + silu ----------------
__global__ __launch_bounds__(256) void conv_silu_k(const float* __restrict__ xc,
    const float* __restrict__ cw, const float* __restrict__ cb, float* __restrict__ u){
  int idx = blockIdx.x * 256 + threadIdx.x;
  int t = idx >> 9, d = idx & 511;
  float acc = cb[d];
  #pragma unroll
  for (int k = 0; k < 4; ++k){
    int ts = t + k - 3;
    if (ts >= 0) acc += xc[(size_t)ts * 512 + d] * cw[d * 4 + k];
  }
  u[idx] = silu_f(acc);
}

// ---------------- dt = softplus(dbc[:, :16] @ w_dt + b_dt) ----------------
__global__ __launch_bounds__(256) void dt_k(const float* __restrict__ dbc,
    const float* __restrict__ w_dt, const float* __restrict__ b_dt, float* __restrict__ dt){
  int idx = blockIdx.x * 256 + threadIdx.x;
  int t = idx >> 9, d = idx & 511;
  float acc = b_dt[d];
  #pragma unroll
  for (int r = 0; r < 16; ++r) acc += dbc[t * 48 + r] * w_dt[r * 512 + d];
  dt[idx] = (acc > 20.f) ? acc : __logf(1.f + __expf(acc));
}

// ---------------- selective scan, chunked (128 chunks x 32 steps) ----------------
// phase 1: local scan from zero state; emit per-chunk carry (decay = exp(A*sum_dt), h_end)
__global__ __launch_bounds__(256) void scan_p1_k(const float* __restrict__ dt,
    const float* __restrict__ u, const float* __restrict__ dbc, const float* __restrict__ A_log,
    float* __restrict__ dAc, float* __restrict__ hend){
  __shared__ float Bl[32 * 16];
  const int c = blockIdx.x;
  const int d = blockIdx.y * 256 + threadIdx.x;
  for (int i = threadIdx.x; i < 512; i += 256)
    Bl[i] = dbc[(size_t)(c * 32 + (i >> 4)) * 48 + 16 + (i & 15)];
  __syncthreads();
  float Aa[16], h[16];
  #pragma unroll
  for (int s = 0; s < 16; ++s){ Aa[s] = -__expf(A_log[d * 16 + s]); h[s] = 0.f; }
  float ds = 0.f;
  for (int t = 0; t < 32; ++t){
    int gt = c * 32 + t;
    float ldt = dt[(size_t)gt * 512 + d];
    float lu  = u [(size_t)gt * 512 + d];
    float dtu = ldt * lu;
    ds += ldt;
    #pragma unroll
    for (int s = 0; s < 16; ++s)
      h[s] = __expf(ldt * Aa[s]) * h[s] + dtu * Bl[t * 16 + s];
  }
  #pragma unroll
  for (int s = 0; s < 16; ++s){
    size_t rec = (size_t)c * 8192 + s * 512 + d;
    dAc[rec]  = __expf(ds * Aa[s]);
    hend[rec] = h[s];
  }
}

// phase 2: wave-parallel Kogge-Stone scan over 128 chunks; one wave per chain.
// lane t locally composes chunks 2t,2t+1; 6 shuffle-scan steps; emit exclusive carries.
__global__ __launch_bounds__(256) void scan_p2_k(const float* __restrict__ dAc,
    const float* __restrict__ hend, float* __restrict__ carry){
  const int chain = blockIdx.x * 4 + (threadIdx.x >> 6);   // 0..8191
  const int lane = threadIdx.x & 63;
  const size_t b0 = (size_t)(lane * 2) * 8192 + chain;
  float a0 = dAc[b0],        e0 = hend[b0];
  float a1 = dAc[b0 + 8192], e1 = hend[b0 + 8192];
  // local pair compose: h -> A*h + B over chunks (2t, 2t+1)
  float A = a0 * a1;
  float B = fmaf(a1, e0, e1);
  // inclusive Kogge-Stone over 64 lanes
  #pragma unroll
  for (int d = 1; d < 64; d <<= 1){
    float Ap = __shfl_up(A, d);
    float Bp = __shfl_up(B, d);
    if (lane >= d){ B = fmaf(A, Bp, B); A *= Ap; }
  }
  // exclusive prefix -> carry into chunk 2t; then step through chunk 2t for 2t+1
  float Bx = __shfl_up(B, 1);
  if (lane == 0) Bx = 0.f;
  carry[b0]        = Bx;
  carry[b0 + 8192] = fmaf(a0, Bx, e0);
}

// phase 3: rescan with carry-in, fused y = sum_s h*C, + u*D_skip, * silu(z)
__global__ __launch_bounds__(256) void scan_p3_k(const float* __restrict__ dt,
    const float* __restrict__ u, const float* __restrict__ z, const float* __restrict__ dbc,
    const float* __restrict__ A_log, const float* __restrict__ Dsk,
    const float* __restrict__ carry, float* __restrict__ yf){
  __shared__ float Bl[32 * 16];
  __shared__ float Cl[32 * 16];
  const int c = blockIdx.x;
  const int d = blockIdx.y * 256 + threadIdx.x;
  for (int i = threadIdx.x; i < 512; i += 256){
    size_t rowb = (size_t)(c * 32 + (i >> 4)) * 48;
    Bl[i] = dbc[rowb + 16 + (i & 15)];
    Cl[i] = dbc[rowb + 32 + (i & 15)];
  }
  __syncthreads();
  float Aa[16], h[16];
  #pragma unroll
  for (int s = 0; s < 16; ++s){
    Aa[s] = -__expf(A_log[d * 16 + s]);
    h[s]  = carry[(size_t)c * 8192 + s * 512 + d];
  }
  const float dsk = Dsk[d];
  for (int t = 0; t < 32; ++t){
    int gt = c * 32 + t;
    float ldt = dt[(size_t)gt * 512 + d];
    float lu  = u [(size_t)gt * 512 + d];
    float lz  = z [(size_t)gt * 512 + d];
    float dtu = ldt * lu;
    float y = 0.f;
    #pragma unroll
    for (int s = 0; s < 16; ++s){
      h[s] = __expf(ldt * Aa[s]) * h[s] + dtu * Bl[t * 16 + s];
      y = fmaf(h[s], Cl[t * 16 + s], y);
    }
    yf[(size_t)gt * 512 + d] = (y + lu * dsk) * silu_f(lz);
  }
}

extern "C" void kernel_launch(void* const* d_in, const int* in_sizes, int n_in,
                              void* d_out, int out_size, void* d_ws, size_t ws_size,
                              hipStream_t stream){
  const float* x      = (const float*)d_in[0];
  const float* adj    = (const float*)d_in[1];
  const float* gcn_w  = (const float*)d_in[2];
  const float* gcn_b  = (const float*)d_in[3];
  const float* ln_g   = (const float*)d_in[4];
  const float* ln_b   = (const float*)d_in[5];
  const float* w_in   = (const float*)d_in[6];
  const float* conv_w = (const float*)d_in[7];
  const float* conv_b = (const float*)d_in[8];
  const float* w_xp   = (const float*)d_in[9];
  const float* w_dt   = (const float*)d_in[10];
  const float* b_dt   = (const float*)d_in[11];
  const float* A_log  = (const float*)d_in[12];
  const float* D_skip = (const float*)d_in[13];
  const float* w_out  = (const float*)d_in[14];
  float* out = (float*)d_out;

  char* w = (char*)d_ws;                       // ~50 MB total (with overlays)
  u16*   xT     = (u16*)(w);                   // 256x4096 bf16
  u16*   gcnT   = (u16*)(w + 2097152);         // 256x256
  u16*   w_inT  = (u16*)(w + 2228224);         // 1024x256
  u16*   w_outT = (u16*)(w + 2752512);         // 256x512
  u16*   w_xpT  = (u16*)(w + 3014656);         // 64x512 (rows 48..63 zero-padded)
  float* G      = (float*)(w + 3080192);       // 4096x256   (dead after K3 -> reused as dAc)
  float* hn     = (float*)(w + 7274496);       // 4096x256   (dead after K4 -> reused as hend)
  float* xc     = (float*)(w + 11468800);      // 4096x512   (dead after K5 -> reused as yf)
  float* zb     = (float*)(w + 19857408);      // 4096x512
  float* ub     = (float*)(w + 28246016);      // 4096x512
  float* dbc    = (float*)(w + 36634624);      // 4096x48
  float* dtb    = (float*)(w + 37421056);      // 4096x512
  float* carry  = (float*)(w + 45809664);      // 128x8192
  float* dAc    = G;
  float* hendb  = hn;
  float* yf     = xc;

  hipMemsetAsync(G,     0, (size_t)4096 * 256 * 4, stream);
  hipMemsetAsync(out,   0, (size_t)4096 * 256 * 4, stream);
  hipMemsetAsync(w_xpT, 0, (size_t)64 * 512 * 2, stream);

  dim3 tb(32, 8);
  transpose_bf16_k<<<dim3(8, 128), tb, 0, stream>>>(x,      xT,     4096, 256);
  transpose_bf16_k<<<dim3(8, 8),   tb, 0, stream>>>(gcn_w,  gcnT,   256,  256);
  transpose_bf16_k<<<dim3(32, 8),  tb, 0, stream>>>(w_in,   w_inT,  256,  1024);
  transpose_bf16_k<<<dim3(8, 16),  tb, 0, stream>>>(w_out,  w_outT, 512,  256);
  transpose_bf16_k<<<dim3(2, 16),  tb, 0, stream>>>(w_xp,   w_xpT,  512,  48);

  // K1: G = adj @ x   (M=4096,K=4096,N=256) split-K=16, atomic accumulate
  gemm_k<0, 64, 256><<<dim3(64, 1, 16), 256, 25600, stream>>>(
      adj, 4096, xT, 4096, 256, G, nullptr, nullptr, nullptr, nullptr);
  // K3: hn = LN(relu(G @ gcn_w + gcn_b))  (TM=16 -> 256 blocks)
  gemm_k<1, 16, 256><<<dim3(256, 1, 1), 256, 38336, stream>>>(
      G, 256, gcnT, 256, 256, hn, nullptr, gcn_b, ln_g, ln_b);
  // K4: xz = hn @ w_in -> xc | z  (TM=32 -> 512 blocks)
  gemm_k<2, 32, 256><<<dim3(128, 4, 1), 256, 23040, stream>>>(
      hn, 256, w_inT, 256, 256, xc, zb, nullptr, nullptr, nullptr);
  // K5: u = silu(depthwise_conv(xc))
  conv_silu_k<<<8192, 256, 0, stream>>>(xc, conv_w, conv_b, ub);
  // K6: dbc = u @ w_xp  (N=48 padded to 64, TM=16 -> 256 blocks)
  gemm_k<3, 16, 64><<<dim3(256, 1, 1), 256, 6400, stream>>>(
      ub, 512, w_xpT, 512, 512, dbc, nullptr, nullptr, nullptr, nullptr);
  // K7: dt = softplus(dbc[:, :16] @ w_dt + b_dt)
  dt_k<<<8192, 256, 0, stream>>>(dbc, w_dt, b_dt, dtb);
  // K8-K10: chunked selective scan
  scan_p1_k<<<dim3(128, 2), 256, 0, stream>>>(dtb, ub, dbc, A_log, dAc, hendb);
  scan_p2_k<<<2048, 256, 0, stream>>>(dAc, hendb, carry);
  scan_p3_k<<<dim3(128, 2), 256, 0, stream>>>(dtb, ub, zb, dbc, A_log, D_skip, carry, yf);
  // K11: out = yf @ w_out  (M=4096,K=512,N=256) split-K=8, atomic
  gemm_k<0, 64, 256><<<dim3(64, 1, 8), 256, 25600, stream>>>(
      yf, 512, w_outT, 512, 64, out, nullptr, nullptr, nullptr, nullptr);
}

// Round 3
// 307.207 us; speedup vs baseline: 1.1312x; 1.1312x over previous
//
#include <hip/hip_runtime.h>
#include <cstddef>
#include <cstdint>

typedef unsigned short u16;
typedef __attribute__((ext_vector_type(8))) unsigned short ushort8;
typedef __attribute__((ext_vector_type(8))) short bf16x8;   // 8 bf16 bit-patterns (4 VGPRs)
typedef __attribute__((ext_vector_type(4))) float f32x4;

#define DEV __device__ __forceinline__

DEV u16 f2bf(float f){
  uint32_t u = __builtin_bit_cast(uint32_t, f);
  u += 0x7FFFu + ((u >> 16) & 1u);          // RNE
  return (u16)(u >> 16);
}
DEV float silu_f(float x){ return x / (1.f + __expf(-x)); }

// ---------------- fused transposes: fp32 [R][C] -> bf16 [Cout][R] ----------------
// one kernel for all 5 weight matrices; w_xp zero-padded to 64 rows.
__global__ __launch_bounds__(256) void prep_k(const float* __restrict__ x,
    const float* __restrict__ gcn_w, const float* __restrict__ w_in,
    const float* __restrict__ w_out, const float* __restrict__ w_xp,
    u16* __restrict__ xT, u16* __restrict__ gcnT, u16* __restrict__ w_inT,
    u16* __restrict__ w_outT, u16* __restrict__ w_xpT){
  __shared__ u16 tile[32][33];
  int b = blockIdx.x;
  const float* in; u16* out; int R, C, Cout, bx, by;
  if (b < 1024)      { in=x;     out=xT;     R=4096; C=256;  Cout=256;  bx=b&7;  by=b>>3; }
  else if (b < 1088) { b-=1024; in=gcn_w; out=gcnT;   R=256; C=256;  Cout=256;  bx=b&7;  by=b>>3; }
  else if (b < 1344) { b-=1088; in=w_in;  out=w_inT;  R=256; C=1024; Cout=1024; bx=b&31; by=b>>5; }
  else if (b < 1472) { b-=1344; in=w_out; out=w_outT; R=512; C=256;  Cout=256;  bx=b&7;  by=b>>3; }
  else               { b-=1472; in=w_xp;  out=w_xpT;  R=512; C=48;   Cout=64;   bx=b&1;  by=b>>1; }
  int c0 = bx*32, r0 = by*32, tx = threadIdx.x, ty = threadIdx.y;   // block (32,8)
  #pragma unroll
  for (int k = 0; k < 4; ++k){
    int r = r0 + ty + k*8, c = c0 + tx;
    float v = (c < C) ? in[(size_t)r * C + c] : 0.f;
    tile[ty + k*8][tx] = f2bf(v);
  }
  __syncthreads();
  #pragma unroll
  for (int k = 0; k < 4; ++k){
    int oc = c0 + ty + k*8, orr = r0 + tx;
    if (oc < Cout) out[(size_t)oc * R + orr] = tile[tx][ty + k*8];
  }
}

// ---------------- generic bf16-MFMA GEMM with register-prefetch pipeline ------
// C[M,N] = A_fp32[M,K] @ B, B pre-transposed bf16 [N][K] (ldb=K).
// NPART>1: A is the sum of NPART partial buffers spaced pastr floats apart.
// MODE: 0 = plain store to out0 + blockIdx.z*postr (256-wide output)
//       1 = +bias, ReLU, LayerNorm(256) -> out0 fp32
//       2 = split store: cols<512 -> out0, else -> out1 (both 512-wide)
template<int MODE, int TM, int NT, int NTHR, int NPART>
__global__ __launch_bounds__(NTHR) void gemm_k(const float* __restrict__ A, int lda, long long pastr,
    const u16* __restrict__ Bt, int ldb, int kchunk,
    float* __restrict__ out0, long long postr, float* __restrict__ out1,
    const float* __restrict__ bias, const float* __restrict__ lng, const float* __restrict__ lnb)
{
  constexpr int NW = NTHR/64, WR = NW/4, WM = TM/WR, WN = NT/4;
  constexpr int MI = WM/16, NI = WN/16;
  extern __shared__ char smem[];
  u16* As = (u16*)smem;                 // TM x 40 (pad 40: 80B rows, 16B-aligned)
  u16* Bs = As + TM * 40;               // NT x 40
  const int tid = threadIdx.x, wave = tid >> 6, lane = tid & 63;
  const int lq = lane >> 4, lr = lane & 15;
  const int wm = wave >> 2, wn = wave & 3;
  const int m0 = blockIdx.x * TM, n0g = blockIdx.y * NT;
  const int k0base = blockIdx.z * kchunk;

  f32x4 acc[MI][NI];
  #pragma unroll
  for (int i = 0; i < MI; ++i)
    #pragma unroll
    for (int j = 0; j < NI; ++j) acc[i][j] = f32x4{0.f, 0.f, 0.f, 0.f};

  const int arow = tid >> 2, ako = (tid & 3) * 8;
  const bool aact = (tid < TM * 4);
  const bool bact = (tid < NT);
  const float* aptr = A + (size_t)(m0 + arow) * lda + k0base + ako;
  const u16*   bptr = Bt + (size_t)(n0g + tid) * ldb + k0base;

  f32x4 fa0[NPART], fa1[NPART];
  ushort8 bv[4];
  if (aact){
    #pragma unroll
    for (int p = 0; p < NPART; ++p){
      fa0[p] = *(const f32x4*)(aptr + (size_t)p * pastr);
      fa1[p] = *(const f32x4*)(aptr + (size_t)p * pastr + 4);
    }
  }
  if (bact){
    const ushort8* bp = (const ushort8*)bptr;
    #pragma unroll
    for (int j = 0; j < 4; ++j) bv[j] = bp[j];
  }

  for (int kk = 0; kk < kchunk; kk += 32){
    if (aact){
      f32x4 s0 = fa0[0], s1 = fa1[0];
      #pragma unroll
      for (int p = 1; p < NPART; ++p){ s0 += fa0[p]; s1 += fa1[p]; }
      ushort8 o;
      #pragma unroll
      for (int j = 0; j < 4; ++j) o[j] = f2bf(s0[j]);
      #pragma unroll
      for (int j = 0; j < 4; ++j) o[4 + j] = f2bf(s1[j]);
      *(ushort8*)(As + arow * 40 + ako) = o;
    }
    if (bact){
      ushort8* dst = (ushort8*)(Bs + tid * 40);
      #pragma unroll
      for (int j = 0; j < 4; ++j) dst[j] = bv[j];
    }
    __syncthreads();
    if (kk + 32 < kchunk){
      aptr += 32; bptr += 32;
      if (aact){
        #pragma unroll
        for (int p = 0; p < NPART; ++p){
          fa0[p] = *(const f32x4*)(aptr + (size_t)p * pastr);
          fa1[p] = *(const f32x4*)(aptr + (size_t)p * pastr + 4);
        }
      }
      if (bact){
        const ushort8* bp = (const ushort8*)bptr;
        #pragma unroll
        for (int j = 0; j < 4; ++j) bv[j] = bp[j];
      }
    }
    bf16x8 af[MI], bfr[NI];
    #pragma unroll
    for (int mi = 0; mi < MI; ++mi)
      af[mi] = *(const bf16x8*)(As + (wm * WM + mi * 16 + lr) * 40 + lq * 8);
    #pragma unroll
    for (int ni = 0; ni < NI; ++ni)
      bfr[ni] = *(const bf16x8*)(Bs + (wn * WN + ni * 16 + lr) * 40 + lq * 8);
    #pragma unroll
    for (int mi = 0; mi < MI; ++mi)
      #pragma unroll
      for (int ni = 0; ni < NI; ++ni)
        acc[mi][ni] = __builtin_amdgcn_mfma_f32_16x16x32_bf16(af[mi], bfr[ni], acc[mi][ni], 0, 0, 0);
    __syncthreads();
  }

  if constexpr (MODE == 1){
    float* Hs  = (float*)(smem + TM * 80 + NT * 80);   // TM x 257
    float* mus = Hs + TM * 257;
    float* rss = mus + TM;
    #pragma unroll
    for (int mi = 0; mi < MI; ++mi)
      #pragma unroll
      for (int ni = 0; ni < NI; ++ni)
        #pragma unroll
        for (int r = 0; r < 4; ++r){
          int row_l = wm*WM + mi*16 + lq*4 + r;
          int col_l = wn*WN + ni*16 + lr;
          Hs[row_l*257 + col_l] = fmaxf(acc[mi][ni][r] + bias[col_l], 0.f);
        }
    __syncthreads();
    for (int r = wave; r < TM; r += NW){
      float s = 0.f, s2 = 0.f;
      #pragma unroll
      for (int j = 0; j < 4; ++j){
        float v = Hs[r*257 + lane + j*64];
        s += v; s2 += v*v;
      }
      #pragma unroll
      for (int d = 32; d; d >>= 1){
        s  += __shfl_down(s, d);
        s2 += __shfl_down(s2, d);
      }
      if (lane == 0){
        float mu  = s * (1.f/256.f);
        float var = s2 * (1.f/256.f) - mu*mu;
        mus[r] = mu; rss[r] = rsqrtf(var + 1e-5f);
      }
    }
    __syncthreads();
    for (int idx = tid; idx < TM*256; idx += NTHR){
      int r = idx >> 8, c = idx & 255;
      float v = (Hs[r*257 + c] - mus[r]) * rss[r] * lng[c] + lnb[c];
      out0[(size_t)(m0 + r) * 256 + c] = v;
    }
  } else {
    #pragma unroll
    for (int mi = 0; mi < MI; ++mi)
      #pragma unroll
      for (int ni = 0; ni < NI; ++ni)
        #pragma unroll
        for (int r = 0; r < 4; ++r){
          float v = acc[mi][ni][r];
          int row  = m0 + wm*WM + mi*16 + lq*4 + r;
          int gcol = n0g + wn*WN + ni*16 + lr;
          if constexpr (MODE == 0){
            out0[(size_t)blockIdx.z * postr + (size_t)row * 256 + gcol] = v;
          } else {
            if (gcol < 512) out0[(size_t)row * 512 + gcol] = v;
            else            out1[(size_t)row * 512 + gcol - 512] = v;
          }
        }
  }
}

// ---------------- fused: conv+silu -> dbc (MFMA) -> dt -> scan phase 1 ----------
// one block (512 thr) per 32-step chunk; thread = channel d.
__global__ __launch_bounds__(512) void mid_k(const float* __restrict__ xc,
    const float* __restrict__ cw, const float* __restrict__ cb,
    const u16* __restrict__ w_xpT, const float* __restrict__ w_dt,
    const float* __restrict__ b_dt, const float* __restrict__ A_log,
    float* __restrict__ u_g, float* __restrict__ dt_g, float* __restrict__ dbc_g,
    float* __restrict__ dAc, float* __restrict__ hend)
{
  __shared__ u16 uL[32 * 520];
  __shared__ float dbcL[32][64];
  const int tid = threadIdx.x, d = tid;
  const int c = blockIdx.x, t0 = c * 32;
  const float w0 = cw[d*4+0], w1 = cw[d*4+1], w2 = cw[d*4+2], w3 = cw[d*4+3];
  const float cbd = cb[d];
  float xm3 = 0.f, xm2 = 0.f, xm1 = 0.f;
  if (c > 0){
    xm3 = xc[(size_t)(t0-3)*512 + d];
    xm2 = xc[(size_t)(t0-2)*512 + d];
    xm1 = xc[(size_t)(t0-1)*512 + d];
  }
  float ureg[32];
  #pragma unroll
  for (int t = 0; t < 32; ++t){
    float x0 = xc[(size_t)(t0+t)*512 + d];
    float a = cbd + xm3*w0 + xm2*w1 + xm1*w2 + x0*w3;
    float uu = silu_f(a);
    ureg[t] = uu;
    uL[t*520 + d] = f2bf(uu);
    u_g[(size_t)(t0+t)*512 + d] = uu;
    xm3 = xm2; xm2 = xm1; xm1 = x0;
  }
  __syncthreads();
  // dbc[32x48(+pad)] = u[32x512] @ w_xp[512x64pad] via MFMA, 8 waves = 2m x 4n tiles
  const int wave = tid >> 6, lane = tid & 63, lq = lane >> 4, lr = lane & 15;
  const int mt = wave >> 2, nt = wave & 3;
  f32x4 dacc{0.f, 0.f, 0.f, 0.f};
  #pragma unroll
  for (int kk = 0; kk < 512; kk += 32){
    bf16x8 aF = *(const bf16x8*)(uL + (mt*16 + lr)*520 + kk + lq*8);
    bf16x8 bF = *(const bf16x8*)(w_xpT + (size_t)(nt*16 + lr)*512 + kk + lq*8);
    dacc = __builtin_amdgcn_mfma_f32_16x16x32_bf16(aF, bF, dacc, 0, 0, 0);
  }
  #pragma unroll
  for (int r = 0; r < 4; ++r) dbcL[mt*16 + lq*4 + r][nt*16 + lr] = dacc[r];
  __syncthreads();
  // store dbc (32x48) for phase 3
  #pragma unroll
  for (int i = tid; i < 32*64; i += 512){
    int r = i >> 6, j = i & 63;
    if (j < 48) dbc_g[(size_t)(t0 + r)*48 + j] = dbcL[r][j];
  }
  // dt = softplus(dbc[:, :16] @ w_dt + b_dt), then local scan from zero state
  float wdt[16];
  #pragma unroll
  for (int r = 0; r < 16; ++r) wdt[r] = w_dt[r*512 + d];
  const float bdt = b_dt[d];
  float Aa[16], h[16];
  #pragma unroll
  for (int s = 0; s < 16; ++s){ Aa[s] = -__expf(A_log[d*16 + s]); h[s] = 0.f; }
  float ds = 0.f;
  #pragma unroll
  for (int t = 0; t < 32; ++t){
    float s = bdt;
    #pragma unroll
    for (int r = 0; r < 16; ++r) s += dbcL[t][r] * wdt[r];
    float ldt = (s > 20.f) ? s : __logf(1.f + __expf(s));
    dt_g[(size_t)(t0+t)*512 + d] = ldt;
    float dtu = ldt * ureg[t];
    ds += ldt;
    #pragma unroll
    for (int k = 0; k < 16; ++k)
      h[k] = __expf(ldt * Aa[k]) * h[k] + dtu * dbcL[t][16 + k];
  }
  #pragma unroll
  for (int s = 0; s < 16; ++s){
    size_t rec = (size_t)c * 8192 + s * 512 + d;
    dAc[rec]  = __expf(ds * Aa[s]);
    hend[rec] = h[s];
  }
}

// ---------------- phase 2: wave-parallel Kogge-Stone over 128 chunk-carries ----
__global__ __launch_bounds__(256) void scan_p2_k(const float* __restrict__ dAc,
    const float* __restrict__ hend, float* __restrict__ carry){
  const int chain = blockIdx.x * 4 + (threadIdx.x >> 6);   // 0..8191
  const int lane = threadIdx.x & 63;
  const size_t b0 = (size_t)(lane * 2) * 8192 + chain;
  float a0 = dAc[b0],        e0 = hend[b0];
  float a1 = dAc[b0 + 8192], e1 = hend[b0 + 8192];
  float A = a0 * a1;
  float B = fmaf(a1, e0, e1);
  #pragma unroll
  for (int d = 1; d < 64; d <<= 1){
    float Ap = __shfl_up(A, d);
    float Bp = __shfl_up(B, d);
    if (lane >= d){ B = fmaf(A, Bp, B); A *= Ap; }
  }
  float Bx = __shfl_up(B, 1);
  if (lane == 0) Bx = 0.f;
  carry[b0]        = Bx;
  carry[b0 + 8192] = fmaf(a0, Bx, e0);
}

// ---------------- phase 3 + output GEMM: rescan w/ carry, gate, y @ w_out ------
__global__ __launch_bounds__(512) void p3out_k(const float* __restrict__ dt,
    const float* __restrict__ u, const float* __restrict__ z,
    const float* __restrict__ dbc_g, const float* __restrict__ A_log,
    const float* __restrict__ Dsk, const float* __restrict__ carry,
    const u16* __restrict__ w_outT, float* __restrict__ out)
{
  __shared__ u16 yL[32 * 520];
  __shared__ float BC[32][32];           // cols 0..15 = B, 16..31 = C
  const int tid = threadIdx.x, d = tid;
  const int c = blockIdx.x, t0 = c * 32;
  for (int i = tid; i < 32*32; i += 512){
    int r = i >> 5, j = i & 31;
    BC[r][j] = dbc_g[(size_t)(t0 + r)*48 + 16 + j];
  }
  float Aa[16], h[16];
  #pragma unroll
  for (int s = 0; s < 16; ++s){
    Aa[s] = -__expf(A_log[d*16 + s]);
    h[s]  = carry[(size_t)c * 8192 + s * 512 + d];
  }
  const float dsk = Dsk[d];
  __syncthreads();
  #pragma unroll
  for (int t = 0; t < 32; ++t){
    size_t g = (size_t)(t0+t)*512 + d;
    float ldt = dt[g], lu = u[g], lz = z[g];
    float dtu = ldt * lu, y = 0.f;
    #pragma unroll
    for (int s = 0; s < 16; ++s){
      h[s] = __expf(ldt * Aa[s]) * h[s] + dtu * BC[t][s];
      y = fmaf(h[s], BC[t][16 + s], y);
    }
    float yv = (y + lu * dsk) * silu_f(lz);
    yL[t*520 + d] = f2bf(yv);
  }
  __syncthreads();
  // out[t0..t0+31, 0..255] = yL[32x512] @ w_out[512x256]
  const int wave = tid >> 6, lane = tid & 63, lq = lane >> 4, lr = lane & 15;
  const int mt = wave >> 2, wn = wave & 3;
  f32x4 acc[4];
  #pragma unroll
  for (int ni = 0; ni < 4; ++ni) acc[ni] = f32x4{0.f, 0.f, 0.f, 0.f};
  #pragma unroll
  for (int kk = 0; kk < 512; kk += 32){
    bf16x8 aF = *(const bf16x8*)(yL + (mt*16 + lr)*520 + kk + lq*8);
    #pragma unroll
    for (int ni = 0; ni < 4; ++ni){
      bf16x8 bF = *(const bf16x8*)(w_outT + (size_t)(wn*64 + ni*16 + lr)*512 + kk + lq*8);
      acc[ni] = __builtin_amdgcn_mfma_f32_16x16x32_bf16(aF, bF, acc[ni], 0, 0, 0);
    }
  }
  #pragma unroll
  for (int ni = 0; ni < 4; ++ni)
    #pragma unroll
    for (int r = 0; r < 4; ++r)
      out[(size_t)(t0 + mt*16 + lq*4 + r)*256 + wn*64 + ni*16 + lr] = acc[ni][r];
}

extern "C" void kernel_launch(void* const* d_in, const int* in_sizes, int n_in,
                              void* d_out, int out_size, void* d_ws, size_t ws_size,
                              hipStream_t stream){
  const float* x      = (const float*)d_in[0];
  const float* adj    = (const float*)d_in[1];
  const float* gcn_w  = (const float*)d_in[2];
  const float* gcn_b  = (const float*)d_in[3];
  const float* ln_g   = (const float*)d_in[4];
  const float* ln_b   = (const float*)d_in[5];
  const float* w_in   = (const float*)d_in[6];
  const float* conv_w = (const float*)d_in[7];
  const float* conv_b = (const float*)d_in[8];
  const float* w_xp   = (const float*)d_in[9];
  const float* w_dt   = (const float*)d_in[10];
  const float* b_dt   = (const float*)d_in[11];
  const float* A_log  = (const float*)d_in[12];
  const float* D_skip = (const float*)d_in[13];
  const float* w_out  = (const float*)d_in[14];
  float* out = (float*)d_out;

  // workspace layout (bytes); overlays exploit dataflow deadness. peak 45.8 MB.
  char* w = (char*)d_ws;
  u16*   xT     = (u16*)(w + 0);          // 2,097,152
  u16*   gcnT   = (u16*)(w + 2097152);    //   131,072
  u16*   w_inT  = (u16*)(w + 2228224);    //   524,288
  u16*   w_outT = (u16*)(w + 2752512);    //   262,144
  u16*   w_xpT  = (u16*)(w + 3014656);    //    65,536
  float* dbc_g  = (float*)(w + 3080192);  //   786,432
  float* G      = (float*)(w + 3866624);  // 16,777,216 : 4 K-split partials (dead after K3)
  float* zb     = (float*)(w + 3866624);  //   overlay: 8,388,608 (written by K4)
  float* u_g    = (float*)(w + 12255232); //   overlay: 8,388,608 (written by mid_k)
  float* hn     = (float*)(w + 20643840); // 4,194,304 (dead after K4)
  float* dAc    = (float*)(w + 20643840); //   overlay (written by mid_k)
  float* xc     = (float*)(w + 24838144); // 8,388,608 (dead after mid_k)
  float* carry  = (float*)(w + 24838144); //   overlay (written by scan_p2)
  float* dt_g   = (float*)(w + 33226752); // 8,388,608
  float* hendb  = (float*)(w + 41615360); // 4,194,304  -> end 45,809,664

  const long long PART = 4096LL * 256;    // partial-buffer stride (floats)

  // 1: all transposes (incl. w_xp zero-pad), no memsets needed anywhere
  prep_k<<<1504, dim3(32, 8), 0, stream>>>(x, gcn_w, w_in, w_out, w_xp,
                                           xT, gcnT, w_inT, w_outT, w_xpT);
  // 2: G[z] = adj @ x partials (M=4096,K=4096,N=256), KS=4, 8 waves/block, no atomics
  gemm_k<0, 64, 256, 512, 1><<<dim3(64, 1, 4), 512, 25600, stream>>>(
      adj, 4096, 0, xT, 4096, 1024, G, PART, nullptr, nullptr, nullptr, nullptr);
  // 3: hn = LN(relu(sum_z G[z] @ gcn_w + gcn_b))
  gemm_k<1, 16, 256, 256, 4><<<dim3(256, 1, 1), 256, 38336, stream>>>(
      G, 256, PART, gcnT, 256, 256, hn, 0, nullptr, gcn_b, ln_g, ln_b);
  // 4: xz = hn @ w_in -> xc | zb
  gemm_k<2, 32, 128, 256, 1><<<dim3(128, 8, 1), 256, 12800, stream>>>(
      hn, 256, 0, w_inT, 256, 256, xc, 0, zb, nullptr, nullptr, nullptr);
  // 5: fused conv+silu + dbc(MFMA) + dt + scan phase 1
  mid_k<<<128, 512, 0, stream>>>(xc, conv_w, conv_b, w_xpT, w_dt, b_dt, A_log,
                                 u_g, dt_g, dbc_g, dAc, hendb);
  // 6: carry propagation
  scan_p2_k<<<2048, 256, 0, stream>>>(dAc, hendb, carry);
  // 7: fused rescan + gate + y @ w_out -> out
  p3out_k<<<128, 512, 0, stream>>>(dt_g, u_g, zb, dbc_g, A_log, D_skip, carry,
                                   w_outT, out);
}